// Round 10
// baseline (217.786 us; speedup 1.0000x reference)
//
#include <hip/hip_runtime.h>
#include <math.h>

// ChamferDistance: B=4, N=M=8192, 3-D fp32 points.
// out[0] = mean_i sqrt(min_j d2)*w  +  mean_j sqrt(min_i d2)
//
// MFMA formulation (R6+): d2 = qsq + (rsq - 2 q.r) as a K=5 dot on
// v_mfma_f32_32x32x16_f16 (32 refs x 32 queries = 1024 pairs/inst):
//   A (refs)    = (-2rx,-2ry,-2rz, rsq_hi, rsq_lo, 0,0,0) f16, lanes 0-31
//   B (queries) = (  qx,  qy,  qz,   1,      1,    0,0,0) f16, lanes 0-31
// lanes 32-63 (k=8..15) zero. D: col=lane&31=query; 16 regs x lane-half =
// 32 refs -> per-lane fminf fold (ISel -> v_min3_f32) + one shfl_xor(32).
//
// R23: single-dispatch via LAST-BLOCK-DONE reduction. Falsification ledger
// (all ~invariant at nn~22us): ILP(R9) dispatch(R10) residency(R11)
// AGPR(R12) pipelining(R13) fold-count(R21: med3 A/B proved fminf chain
// already min3-fused at 0.5 instr/value) setprio(R16) A-prefetch depth-2
// (R22). Budget: fill ~40 (harness ws poison, fixed) + nn ~22 + reduce ~5
// + gaps ~8 (cross-checked vs R18: 40+47+11=100.8). Attack the reduce
// dispatch + gap: after a block stores its chunk partials, threadfence +
// bump counter[zb][qgroup]; 8th block of the group reduces its 256 queries
// (min over 8 partials -> sqrt -> weight -> block sum, EXACT verified
// shuffle tree) and atomicAdds fsum; 256th group writes out[0]. Counters+
// fsum zeroed by ONE 1KB hipMemsetAsync (capturable; R18 precedent).
// Per-256-query block-sum + atomicAdd order is PROVEN safe: R17+R18 both
// absmax 0.0 with exactly this order. K-loop = verified R13 shape.
// Predict: 75.0 -> ~67-70us, absmax 0.0. If ~0 delta: gap model wrong,
// session at practical floor.
// NEVER read MFMA D regs via inline asm (R14/R15 race).

#define EPS 1e-8f

typedef _Float16 f16x8 __attribute__((ext_vector_type(8)));
typedef float    f32x16 __attribute__((ext_vector_type(16)));

constexpr int B_    = 4;
constexpr int N_    = 8192;          // points per batch (N == M)
constexpr int TPB   = 256;           // 4 waves
constexpr int QPW   = 64;            // queries per wave (2 tiles of 32)
constexpr int QPB   = 4 * QPW;       // 256 queries per block (== TPB)
constexpr int RCH   = 8;             // ref chunks (grid.y)
constexpr int CHUNK = N_ / RCH;      // 1024 refs staged per block (16 KB)
constexpr int NGRP  = 8 * 32;        // (zb, qgroup) completion groups

// Verified fold: exact min, order-free; clang fuses fminf(fminf(a,b),acc)
// to v_min3_f32 (PROVEN at floor by the R21 med3 A/B). DO NOT replace
// with inline asm (R14/R15 race) or med3 (R21: 2x fold ops).
#define FOLD(d, ma, mb)                                         \
    _Pragma("unroll")                                           \
    for (int r = 0; r < 8; r += 2)                              \
        ma = fminf(fminf(d[r], d[r + 1]), ma);                  \
    _Pragma("unroll")                                           \
    for (int r = 8; r < 16; r += 2)                             \
        mb = fminf(fminf(d[r], d[r + 1]), mb);

// grid: (N/QPB=32, RCH=8, 2*B=8) = 2048 blocks.
// part layout: part[(zb*RCH + c)*N + q]  (zb = dir*4+b), 2 MB total.
__global__ __launch_bounds__(TPB, 4)
void nn_mfma_kernel(const float* __restrict__ src, const float* __restrict__ tgt,
                    const float* __restrict__ w, float* __restrict__ part,
                    unsigned* __restrict__ counters, float* __restrict__ fsum,
                    float* __restrict__ out)
{
    __shared__ f16x8 sref[CHUNK + 64];   // +64: zero slots (also absorb tail reads)
    __shared__ float ss[TPB / 64];
    __shared__ int   isLast;

    const int zb  = blockIdx.z;
    const int dir = zb >> 2;            // 0: src queries tgt, 1: tgt queries src
    const int b   = zb & 3;
    const float* Rraw = (dir ? src : tgt) + ((size_t)b * N_ + (size_t)blockIdx.y * CHUNK) * 3;
    const float* Qraw = (dir ? tgt : src) + (size_t)b * N_ * 3;
    float* opart = part + ((size_t)zb * RCH + blockIdx.y) * N_;

    const int tid = threadIdx.x;
    const _Float16 h0 = (_Float16)0.f;
    const _Float16 h1 = (_Float16)1.f;

    // stage + quantize refs inline: (-2x,-2y,-2z, rsq_hi, rsq_lo, 0,0,0)
    for (int k = tid; k < CHUNK; k += TPB) {
        const float* rp = Rraw + (size_t)k * 3;
        _Float16 hx = (_Float16)rp[0], hy = (_Float16)rp[1], hz = (_Float16)rp[2];
        float fx = (float)hx, fy = (float)hy, fz = (float)hz;
        float rsq = fx * fx + fy * fy + fz * fz;
        _Float16 rh = (_Float16)rsq;
        _Float16 rl = (_Float16)(rsq - (float)rh);
        f16x8 a = {(_Float16)(-2.f * fx), (_Float16)(-2.f * fy),
                   (_Float16)(-2.f * fz), rh, rl, h0, h0, h0};
        sref[k] = a;
    }
    if (tid < 64) {
        f16x8 z = {h0, h0, h0, h0, h0, h0, h0, h0};
        sref[CHUNK + tid] = z;
    }

    const int lane = tid & 63;
    const int wv   = tid >> 6;
    const int l31  = lane & 31;
    const int half = lane >> 5;          // 0: carries data (k=0..7), 1: zeros
    const int qb   = blockIdx.x * QPB + wv * QPW;

    // B fragments quantized inline; lanes 32-63 stay zero (k=8..15)
    f16x8 B0 = {h0, h0, h0, h0, h0, h0, h0, h0};
    f16x8 B1 = B0;
    float qs0 = 0.f, qs1 = 0.f;
    if (half == 0) {
        const float* q0 = Qraw + (size_t)(qb + l31) * 3;
        const float* q1 = Qraw + (size_t)(qb + 32 + l31) * 3;
        _Float16 ax = (_Float16)q0[0], ay = (_Float16)q0[1], az = (_Float16)q0[2];
        _Float16 bx = (_Float16)q1[0], by = (_Float16)q1[1], bz = (_Float16)q1[2];
        float fax = (float)ax, fay = (float)ay, faz = (float)az;
        float fbx = (float)bx, fby = (float)by, fbz = (float)bz;
        B0 = f16x8{ax, ay, az, h1, h1, h0, h0, h0};
        B1 = f16x8{bx, by, bz, h1, h1, h0, h0, h0};
        qs0 = fax * fax + fay * fay + faz * faz;
        qs1 = fbx * fbx + fby * fby + fbz * fbz;
    }
    __syncthreads();

    const f32x16 zc = {};

    // Depth-1 pipelined K-loop over 32 A-fragments, unrolled x2 (ping-pong,
    // no register copies): fold fragment k-1's D while fragment k's MFMAs
    // are in flight. (R13-verified shape.)
    int idx = (half == 0) ? l31 : CHUNK;
    const int step = (half == 0) ? 32 : 0;
    float mn0a = 3.0e38f, mn0b = 3.0e38f, mn1a = 3.0e38f, mn1b = 3.0e38f;

    f16x8 a = sref[idx];
    idx += step;
    f32x16 dA0 = __builtin_amdgcn_mfma_f32_32x32x16_f16(a, B0, zc, 0, 0, 0);
    f32x16 dA1 = __builtin_amdgcn_mfma_f32_32x32x16_f16(a, B1, zc, 0, 0, 0);
    a = sref[idx];
    idx += step;
    for (int s = 0; s < 15; ++s) {
        f32x16 dB0 = __builtin_amdgcn_mfma_f32_32x32x16_f16(a, B0, zc, 0, 0, 0);
        f32x16 dB1 = __builtin_amdgcn_mfma_f32_32x32x16_f16(a, B1, zc, 0, 0, 0);
        a = sref[idx];
        idx += step;
        FOLD(dA0, mn0a, mn0b)
        FOLD(dA1, mn1a, mn1b)
        dA0 = __builtin_amdgcn_mfma_f32_32x32x16_f16(a, B0, zc, 0, 0, 0);
        dA1 = __builtin_amdgcn_mfma_f32_32x32x16_f16(a, B1, zc, 0, 0, 0);
        a = sref[idx];
        idx += step;
        FOLD(dB0, mn0a, mn0b)
        FOLD(dB1, mn1a, mn1b)
    }
    {
        f32x16 dB0 = __builtin_amdgcn_mfma_f32_32x32x16_f16(a, B0, zc, 0, 0, 0);
        f32x16 dB1 = __builtin_amdgcn_mfma_f32_32x32x16_f16(a, B1, zc, 0, 0, 0);
        FOLD(dA0, mn0a, mn0b)
        FOLD(dA1, mn1a, mn1b)
        FOLD(dB0, mn0a, mn0b)
        FOLD(dB1, mn1a, mn1b)
    }

    float mn0 = fminf(mn0a, mn0b);
    float mn1 = fminf(mn1a, mn1b);
    // rows split across lane halves: one xor-32 merge covers all 32 refs/tile
    mn0 = fminf(mn0, __shfl_xor(mn0, 32));
    mn1 = fminf(mn1, __shfl_xor(mn1, 32));
    if (half == 0) {
        opart[qb + l31]      = fmaxf(mn0 + qs0, 0.f);   // plain store, no init
        opart[qb + 32 + l31] = fmaxf(mn1 + qs1, 0.f);
    }

    // ---- completion protocol: 8th block of group (zb, blockIdx.x) reduces
    __threadfence();                     // my partial stores -> device-visible
    __syncthreads();                     // all threads' stores fenced
    if (tid == 0) {
        unsigned old = atomicAdd(&counters[zb * 32 + blockIdx.x], 1u);
        isLast = (old == RCH - 1);
    }
    __syncthreads();
    if (!isLast) return;

    __threadfence();                     // acquire: other blocks' partials
    const int qn = blockIdx.x * QPB + tid;   // QPB == TPB: 1 query/thread
    const float* p = part + ((size_t)zb * RCH) * N_ + qn;
    float m = p[0];
#pragma unroll
    for (int c = 1; c < RCH; ++c) m = fminf(m, p[(size_t)c * N_]);
    float d = sqrtf(m + EPS);
    float val = dir ? d : d * w[(size_t)b * N_ + qn];
#pragma unroll
    for (int off = 32; off > 0; off >>= 1) val += __shfl_down(val, off);
    if (lane == 0) ss[wv] = val;
    __syncthreads();
    if (tid == 0) {
        float s = ss[0] + ss[1] + ss[2] + ss[3];
        atomicAdd(fsum, s * (1.0f / (float)(B_ * N_)));
        __threadfence();                 // fsum add ordered before gcount bump
        unsigned og = atomicAdd(&counters[NGRP], 1u);   // global group counter
        if (og == NGRP - 1) {
            __threadfence();
            out[0] = atomicAdd(fsum, 0.0f);   // coherent read of final total
        }
    }
}

extern "C" void kernel_launch(void* const* d_in, const int* in_sizes, int n_in,
                              void* d_out, int out_size, void* d_ws, size_t ws_size,
                              hipStream_t stream)
{
    const float* src = (const float*)d_in[0];   // (B, N, 3)
    const float* tgt = (const float*)d_in[1];   // (B, M, 3)
    const float* w   = (const float*)d_in[2];   // (B, N)
    float* out = (float*)d_out;

    float*    part     = (float*)d_ws;                       // 2 MB partials
    unsigned* counters = (unsigned*)((char*)d_ws + (size_t)2 * B_ * RCH * N_ * 4);
    float*    fsum     = (float*)(counters + NGRP + 1);      // after counters+gcount

    // zero counters[256] + gcount + fsum in ONE capturable memset (1032 B)
    hipMemsetAsync(counters, 0, (NGRP + 2) * sizeof(unsigned), stream);

    dim3 grid(N_ / QPB, RCH, 2 * B_);   // 32 x 8 x 8 = 2048 blocks
    nn_mfma_kernel<<<grid, TPB, 0, stream>>>(src, tgt, w, part, counters, fsum, out);
}

// Round 11
// 75.334 us; speedup vs baseline: 2.8910x; 2.8910x over previous
//
#include <hip/hip_runtime.h>
#include <math.h>

// ChamferDistance: B=4, N=M=8192, 3-D fp32 points.
// out[0] = mean_i sqrt(min_j d2)*w  +  mean_j sqrt(min_i d2)
//
// MFMA formulation (R6+): d2 = qsq + (rsq - 2 q.r) as a K=5 dot on
// v_mfma_f32_32x32x16_f16 (32 refs x 32 queries = 1024 pairs/inst):
//   A (refs)    = (-2rx,-2ry,-2rz, rsq_hi, rsq_lo, 0,0,0) f16, lanes 0-31
//   B (queries) = (  qx,  qy,  qz,   1,      1,    0,0,0) f16, lanes 0-31
// lanes 32-63 (k=8..15) zero. D: col=lane&31=query; 16 regs x lane-half =
// 32 refs -> per-lane fminf fold (ISel -> v_min3_f32) + one shfl_xor(32).
//
// R24: RCH 8->4 (CHUNK 2048). R23's single-dispatch fused epilogue
// regressed 7.5x: VGPR_Count fell to 40 -> allocator moved the f32x16
// accumulators to AGPRs (unified file) and every fold paid MFMA->AGPR
// hazard + move costs (MfmaUtil 4%). REVERTED; lesson: epilogue register
// pressure can silently re-class accumulators — keep nn's epilogue
// minimal. This round cleanly tests the per-block-prologue theory that
// R17/R18 bundled with confounds: same wave shape, same inner K-loop,
// same 4 blocks/CU (LDS 33KB x4 = 132 <= 160KB), but 4 sequential block
// prologues per CU instead of 8 (staging/Q-setup/barrier/drain events
// halve; staged bytes unchanged). Numerics BIT-IDENTICAL: min over 4
// partitions == min over 8 (exact, partition-invariant); reduce keeps the
// identical t-mapping and sum order (only RCH in the min loop changes).
// Falsification ledger (all ~invariant at nn~22us): ILP(R9) dispatch(R10)
// residency(R11) AGPR(R12) pipelining(R13) fold-count(R21 med3: fminf
// already min3-fused at floor) setprio(R16) A-prefetch(R22) fused-
// epilogue(R23 regression). Predict: nn 22->~17us, total ~70-71us if
// per-block overhead real; flat ~75 -> declare practical floor.
// NEVER read MFMA D regs via inline asm (R14/R15 race).

#define EPS 1e-8f

typedef _Float16 f16x8 __attribute__((ext_vector_type(8)));
typedef float    f32x16 __attribute__((ext_vector_type(16)));

constexpr int B_    = 4;
constexpr int N_    = 8192;          // points per batch (N == M)
constexpr int TPB   = 256;           // 4 waves
constexpr int QPW   = 64;            // queries per wave (2 tiles of 32)
constexpr int QPB   = 4 * QPW;       // 256 queries per block
constexpr int RCH   = 4;             // ref chunks (grid.y)  [R24: was 8]
constexpr int CHUNK = N_ / RCH;      // 2048 refs staged per block (32 KB)
constexpr int NFRAG = CHUNK / 32;    // 64 A-fragments per wave-tile
constexpr int RB    = 64;            // reduce blocks (R13-verified order)

// Verified fold: exact min, order-free; clang fuses fminf(fminf(a,b),acc)
// to v_min3_f32 (PROVEN at floor by the R21 med3 A/B). DO NOT replace
// with inline asm (R14/R15 race) or med3 (R21: 2x fold ops).
#define FOLD(d, ma, mb)                                         \
    _Pragma("unroll")                                           \
    for (int r = 0; r < 8; r += 2)                              \
        ma = fminf(fminf(d[r], d[r + 1]), ma);                  \
    _Pragma("unroll")                                           \
    for (int r = 8; r < 16; r += 2)                             \
        mb = fminf(fminf(d[r], d[r + 1]), mb);

// grid: (N/QPB=32, RCH=4, 2*B=8) = 1024 blocks.
// part layout: part[(zb*RCH + c)*N + q]  (zb = dir*4+b), 1 MB total.
__global__ __launch_bounds__(TPB, 4)
void nn_mfma_kernel(const float* __restrict__ src, const float* __restrict__ tgt,
                    float* __restrict__ part, float* __restrict__ out)
{
    __shared__ f16x8 sref[CHUNK + 64];   // +64: zero slots (also absorb tail reads)

    if (blockIdx.x == 0 && blockIdx.y == 0 && blockIdx.z == 0 && threadIdx.x == 0)
        out[0] = 0.f;                    // reduce (next dispatch) atomicAdds

    const int zb  = blockIdx.z;
    const int dir = zb >> 2;            // 0: src queries tgt, 1: tgt queries src
    const int b   = zb & 3;
    const float* Rraw = (dir ? src : tgt) + ((size_t)b * N_ + (size_t)blockIdx.y * CHUNK) * 3;
    const float* Qraw = (dir ? tgt : src) + (size_t)b * N_ * 3;
    float* opart = part + ((size_t)zb * RCH + blockIdx.y) * N_;

    const int tid = threadIdx.x;
    const _Float16 h0 = (_Float16)0.f;
    const _Float16 h1 = (_Float16)1.f;

    // stage + quantize refs inline: (-2x,-2y,-2z, rsq_hi, rsq_lo, 0,0,0)
    for (int k = tid; k < CHUNK; k += TPB) {
        const float* rp = Rraw + (size_t)k * 3;
        _Float16 hx = (_Float16)rp[0], hy = (_Float16)rp[1], hz = (_Float16)rp[2];
        float fx = (float)hx, fy = (float)hy, fz = (float)hz;
        float rsq = fx * fx + fy * fy + fz * fz;
        _Float16 rh = (_Float16)rsq;
        _Float16 rl = (_Float16)(rsq - (float)rh);
        f16x8 a = {(_Float16)(-2.f * fx), (_Float16)(-2.f * fy),
                   (_Float16)(-2.f * fz), rh, rl, h0, h0, h0};
        sref[k] = a;
    }
    if (tid < 64) {
        f16x8 z = {h0, h0, h0, h0, h0, h0, h0, h0};
        sref[CHUNK + tid] = z;
    }

    const int lane = tid & 63;
    const int wv   = tid >> 6;
    const int l31  = lane & 31;
    const int half = lane >> 5;          // 0: carries data (k=0..7), 1: zeros
    const int qb   = blockIdx.x * QPB + wv * QPW;

    // B fragments quantized inline; lanes 32-63 stay zero (k=8..15)
    f16x8 B0 = {h0, h0, h0, h0, h0, h0, h0, h0};
    f16x8 B1 = B0;
    float qs0 = 0.f, qs1 = 0.f;
    if (half == 0) {
        const float* q0 = Qraw + (size_t)(qb + l31) * 3;
        const float* q1 = Qraw + (size_t)(qb + 32 + l31) * 3;
        _Float16 ax = (_Float16)q0[0], ay = (_Float16)q0[1], az = (_Float16)q0[2];
        _Float16 bx = (_Float16)q1[0], by = (_Float16)q1[1], bz = (_Float16)q1[2];
        float fax = (float)ax, fay = (float)ay, faz = (float)az;
        float fbx = (float)bx, fby = (float)by, fbz = (float)bz;
        B0 = f16x8{ax, ay, az, h1, h1, h0, h0, h0};
        B1 = f16x8{bx, by, bz, h1, h1, h0, h0, h0};
        qs0 = fax * fax + fay * fay + faz * faz;
        qs1 = fbx * fbx + fby * fby + fbz * fbz;
    }
    __syncthreads();

    const f32x16 zc = {};

    // Depth-1 pipelined K-loop over NFRAG=64 A-fragments, unrolled x2
    // (ping-pong, no register copies): fold fragment k-1's D while
    // fragment k's MFMAs are in flight. Reads f0..f63 exactly; last deref
    // at l31+2016 < CHUNK. (R13-verified shape, doubled trip count.)
    int idx = (half == 0) ? l31 : CHUNK;
    const int step = (half == 0) ? 32 : 0;
    float mn0a = 3.0e38f, mn0b = 3.0e38f, mn1a = 3.0e38f, mn1b = 3.0e38f;

    f16x8 a = sref[idx];
    idx += step;
    f32x16 dA0 = __builtin_amdgcn_mfma_f32_32x32x16_f16(a, B0, zc, 0, 0, 0);
    f32x16 dA1 = __builtin_amdgcn_mfma_f32_32x32x16_f16(a, B1, zc, 0, 0, 0);
    a = sref[idx];
    idx += step;
    for (int s = 0; s < NFRAG / 2 - 1; ++s) {
        f32x16 dB0 = __builtin_amdgcn_mfma_f32_32x32x16_f16(a, B0, zc, 0, 0, 0);
        f32x16 dB1 = __builtin_amdgcn_mfma_f32_32x32x16_f16(a, B1, zc, 0, 0, 0);
        a = sref[idx];
        idx += step;
        FOLD(dA0, mn0a, mn0b)
        FOLD(dA1, mn1a, mn1b)
        dA0 = __builtin_amdgcn_mfma_f32_32x32x16_f16(a, B0, zc, 0, 0, 0);
        dA1 = __builtin_amdgcn_mfma_f32_32x32x16_f16(a, B1, zc, 0, 0, 0);
        a = sref[idx];
        idx += step;
        FOLD(dB0, mn0a, mn0b)
        FOLD(dB1, mn1a, mn1b)
    }
    {
        f32x16 dB0 = __builtin_amdgcn_mfma_f32_32x32x16_f16(a, B0, zc, 0, 0, 0);
        f32x16 dB1 = __builtin_amdgcn_mfma_f32_32x32x16_f16(a, B1, zc, 0, 0, 0);
        FOLD(dA0, mn0a, mn0b)
        FOLD(dA1, mn1a, mn1b)
        FOLD(dB0, mn0a, mn0b)
        FOLD(dB1, mn1a, mn1b)
    }

    float mn0 = fminf(mn0a, mn0b);
    float mn1 = fminf(mn1a, mn1b);
    // rows split across lane halves: one xor-32 merge covers all 32 refs/tile
    mn0 = fminf(mn0, __shfl_xor(mn0, 32));
    mn1 = fminf(mn1, __shfl_xor(mn1, 32));
    if (half == 0) {
        opart[qb + l31]      = fmaxf(mn0 + qs0, 0.f);   // plain store, no init
        opart[qb + 32 + l31] = fmaxf(mn1 + qs1, 0.f);
    }
}

// reduce: per query min over RCH partials -> sqrt -> weight -> sum ->
// atomicAdd into out[0] (zeroed by nn). 1 MB of partials, L2-resident.
// R13-verified t-mapping and summation order (absmax 0.0) — only the min
// trip count changed (4 partitions of the same refs -> identical min).
__global__ __launch_bounds__(TPB)
void reduce_kernel(const float* __restrict__ part,
                   const float* __restrict__ w,
                   float* __restrict__ out)
{
    const int Q = 2 * B_ * N_;               // 65536 queries
    const float invBN = 1.0f / (float)(B_ * N_);

    float sum = 0.0f;
    for (int t = blockIdx.x * TPB + threadIdx.x; t < Q; t += RB * TPB) {
        const int zb = t >> 13;              // t / N_
        const int qn = t & (N_ - 1);
        const float* p = part + ((size_t)zb * RCH) * N_ + qn;
        float m = p[0];
#pragma unroll
        for (int c = 1; c < RCH; ++c) m = fminf(m, p[(size_t)c * N_]);
        float d = sqrtf(m + EPS);
        sum += (zb < 4) ? d * w[(size_t)zb * N_ + qn] : d;
    }
    sum *= invBN;

    __shared__ float ss[TPB / 64];
    int lane = threadIdx.x & 63;
    int wid  = threadIdx.x >> 6;
#pragma unroll
    for (int off = 32; off > 0; off >>= 1) sum += __shfl_down(sum, off);
    if (lane == 0) ss[wid] = sum;
    __syncthreads();
    if (threadIdx.x == 0) {
        float s = 0.0f;
#pragma unroll
        for (int i = 0; i < TPB / 64; ++i) s += ss[i];
        atomicAdd(out, s);
    }
}

extern "C" void kernel_launch(void* const* d_in, const int* in_sizes, int n_in,
                              void* d_out, int out_size, void* d_ws, size_t ws_size,
                              hipStream_t stream)
{
    const float* src = (const float*)d_in[0];   // (B, N, 3)
    const float* tgt = (const float*)d_in[1];   // (B, M, 3)
    const float* w   = (const float*)d_in[2];   // (B, N)
    float* out = (float*)d_out;

    float* part = (float*)d_ws;   // [2*B][RCH][N] = 1 MB, fully overwritten

    dim3 grid(N_ / QPB, RCH, 2 * B_);   // 32 x 4 x 8 = 1024 blocks
    nn_mfma_kernel<<<grid, TPB, 0, stream>>>(src, tgt, part, out);

    reduce_kernel<<<RB, TPB, 0, stream>>>(part, w, out);
}

// Round 12
// 74.899 us; speedup vs baseline: 2.9077x; 1.0058x over previous
//
#include <hip/hip_runtime.h>
#include <math.h>

// ChamferDistance: B=4, N=M=8192, 3-D fp32 points.
// out[0] = mean_i sqrt(min_j d2)*w  +  mean_j sqrt(min_i d2)
//
// MFMA formulation (R6+): d2 = qsq + (rsq - 2 q.r) as a K=5 dot on
// v_mfma_f32_32x32x16_f16 (32 refs x 32 queries = 1024 pairs/inst):
//   A (refs)    = (-2rx,-2ry,-2rz, rsq_hi, rsq_lo, 0,0,0) f16, lanes 0-31
//   B (queries) = (  qx,  qy,  qz,   1,      1,    0,0,0) f16, lanes 0-31
// lanes 32-63 (k=8..15) zero. D: col=lane&31=query; 16 regs x lane-half =
// 32 refs -> per-lane fminf fold (ISel -> v_min3_f32) + one shfl_xor(32).
//
// R25: TLP experiment — 8 waves/SIMD via QPW 64->32, TPB 256->512.
// Recalibrated model (R18's measured 33.8 SIMD-cyc/mfma): per SIMD the
// serial pipe sum is MAI 7.25us + VALU 3.4us + ds 1.3us ~= 12us; measured
// nn ~22 matches NO cross-pipe overlap + overhead, while overlapped floor
// is ~7.5us. m114 proved MAI/VALU co-schedule ACROSS waves — but VGPR=108
// capped us at 4 waves/SIMD, all barrier-aligned in one block -> lockstep
// phases, nothing to overlap. All 13 falsified levers (ILP R9, dispatch
// R10, residency R11, AGPR R12, pipelining R13, fold-count R21-med3 [fminf
// already min3-fused at floor], setprio R16, A-prefetch R22, fused-epilogue
// R23 [VGPR reclass regression], prologue-count R24) rearranged WITHIN the
// lockstep. This buys phase diversity instead: 1 B-tile/wave halves D regs
// (VGPR ~60), launch_bounds(512,8) requests the 64-VGPR class = 8 waves/
// SIMD = 32 waves/CU cap. Grid/QPB/fragment order/fold order/stores
// unchanged -> bit-identical numerics. ds_reads double (+1.3us pipe work).
// Predict: nn 22 -> ~14-16us, total ~68-70. Flat ~75 -> intrinsic
// serialization, declare floor. Spills (WRITE_SIZE GB-scale, R17
// signature) -> fallback launch_bounds(512,4).
// NEVER read MFMA D regs via inline asm (R14/R15 race).

#define EPS 1e-8f

typedef _Float16 f16x8 __attribute__((ext_vector_type(8)));
typedef float    f32x16 __attribute__((ext_vector_type(16)));

constexpr int B_    = 4;
constexpr int N_    = 8192;          // points per batch (N == M)
constexpr int TPB   = 512;           // 8 waves  [R25: was 256/4]
constexpr int QPW   = 32;            // queries per wave (1 MFMA tile) [was 64/2]
constexpr int QPB   = 8 * QPW;       // 256 queries per block (unchanged)
constexpr int RCH   = 8;             // ref chunks (grid.y)
constexpr int CHUNK = N_ / RCH;      // 1024 refs staged per block (16 KB)
constexpr int RB    = 64;            // reduce blocks (R13-verified order)

// Verified fold: exact min, order-free; clang fuses fminf(fminf(a,b),acc)
// to v_min3_f32 (PROVEN at floor by the R21 med3 A/B). DO NOT replace
// with inline asm (R14/R15 race) or med3 (R21: 2x fold ops).
#define FOLD(d, ma, mb)                                         \
    _Pragma("unroll")                                           \
    for (int r = 0; r < 8; r += 2)                              \
        ma = fminf(fminf(d[r], d[r + 1]), ma);                  \
    _Pragma("unroll")                                           \
    for (int r = 8; r < 16; r += 2)                             \
        mb = fminf(fminf(d[r], d[r + 1]), mb);

// grid: (N/QPB=32, RCH=8, 2*B=8) = 2048 blocks (unchanged).
// part layout: part[(zb*RCH + c)*N + q]  (zb = dir*4+b), 2 MB total.
__global__ __launch_bounds__(TPB, 8)
void nn_mfma_kernel(const float* __restrict__ src, const float* __restrict__ tgt,
                    float* __restrict__ part, float* __restrict__ out)
{
    __shared__ f16x8 sref[CHUNK + 64];   // +64: zero slots (also absorb tail reads)

    if (blockIdx.x == 0 && blockIdx.y == 0 && blockIdx.z == 0 && threadIdx.x == 0)
        out[0] = 0.f;                    // reduce (next dispatch) atomicAdds

    const int zb  = blockIdx.z;
    const int dir = zb >> 2;            // 0: src queries tgt, 1: tgt queries src
    const int b   = zb & 3;
    const float* Rraw = (dir ? src : tgt) + ((size_t)b * N_ + (size_t)blockIdx.y * CHUNK) * 3;
    const float* Qraw = (dir ? tgt : src) + (size_t)b * N_ * 3;
    float* opart = part + ((size_t)zb * RCH + blockIdx.y) * N_;

    const int tid = threadIdx.x;
    const _Float16 h0 = (_Float16)0.f;
    const _Float16 h1 = (_Float16)1.f;

    // stage + quantize refs inline: (-2x,-2y,-2z, rsq_hi, rsq_lo, 0,0,0)
    for (int k = tid; k < CHUNK; k += TPB) {
        const float* rp = Rraw + (size_t)k * 3;
        _Float16 hx = (_Float16)rp[0], hy = (_Float16)rp[1], hz = (_Float16)rp[2];
        float fx = (float)hx, fy = (float)hy, fz = (float)hz;
        float rsq = fx * fx + fy * fy + fz * fz;
        _Float16 rh = (_Float16)rsq;
        _Float16 rl = (_Float16)(rsq - (float)rh);
        f16x8 a = {(_Float16)(-2.f * fx), (_Float16)(-2.f * fy),
                   (_Float16)(-2.f * fz), rh, rl, h0, h0, h0};
        sref[k] = a;
    }
    if (tid < 64) {
        f16x8 z = {h0, h0, h0, h0, h0, h0, h0, h0};
        sref[CHUNK + tid] = z;
    }

    const int lane = tid & 63;
    const int wv   = tid >> 6;           // 0..7
    const int l31  = lane & 31;
    const int half = lane >> 5;          // 0: carries data (k=0..7), 1: zeros
    const int qb   = blockIdx.x * QPB + wv * QPW;

    // B fragment quantized inline; lanes 32-63 stay zero (k=8..15)
    f16x8 B0 = {h0, h0, h0, h0, h0, h0, h0, h0};
    float qs0 = 0.f;
    if (half == 0) {
        const float* q0 = Qraw + (size_t)(qb + l31) * 3;
        _Float16 ax = (_Float16)q0[0], ay = (_Float16)q0[1], az = (_Float16)q0[2];
        float fax = (float)ax, fay = (float)ay, faz = (float)az;
        B0 = f16x8{ax, ay, az, h1, h1, h0, h0, h0};
        qs0 = fax * fax + fay * fay + faz * faz;
    }
    __syncthreads();

    const f32x16 zc = {};

    // Depth-1 pipelined K-loop over 32 A-fragments, unrolled x2 (ping-pong,
    // no register copies): fold fragment k-1's D while fragment k's MFMAs
    // are in flight. Same fragment order and fold order as the verified
    // R13 shape — only tiles-per-wave changed (2 -> 1): bit-identical.
    int idx = (half == 0) ? l31 : CHUNK;
    const int step = (half == 0) ? 32 : 0;
    float mn0a = 3.0e38f, mn0b = 3.0e38f;

    f16x8 a = sref[idx];
    idx += step;
    f32x16 dA0 = __builtin_amdgcn_mfma_f32_32x32x16_f16(a, B0, zc, 0, 0, 0);
    a = sref[idx];
    idx += step;
    for (int s = 0; s < 15; ++s) {
        f32x16 dB0 = __builtin_amdgcn_mfma_f32_32x32x16_f16(a, B0, zc, 0, 0, 0);
        a = sref[idx];
        idx += step;
        FOLD(dA0, mn0a, mn0b)
        dA0 = __builtin_amdgcn_mfma_f32_32x32x16_f16(a, B0, zc, 0, 0, 0);
        a = sref[idx];
        idx += step;
        FOLD(dB0, mn0a, mn0b)
    }
    {
        f32x16 dB0 = __builtin_amdgcn_mfma_f32_32x32x16_f16(a, B0, zc, 0, 0, 0);
        FOLD(dA0, mn0a, mn0b)
        FOLD(dB0, mn0a, mn0b)
    }

    float mn0 = fminf(mn0a, mn0b);
    // rows split across lane halves: one xor-32 merge covers all 32 refs/tile
    mn0 = fminf(mn0, __shfl_xor(mn0, 32));
    if (half == 0)
        opart[qb + l31] = fmaxf(mn0 + qs0, 0.f);   // plain store, no init
}

// reduce: per query min over RCH partials -> sqrt -> weight -> sum ->
// atomicAdd into out[0] (zeroed by nn). 2 MB of partials, L2-resident.
// R13-verified summation order (absmax 0.0) — keep byte-identical.
__global__ __launch_bounds__(256)
void reduce_kernel(const float* __restrict__ part,
                   const float* __restrict__ w,
                   float* __restrict__ out)
{
    const int Q = 2 * B_ * N_;               // 65536 queries
    const float invBN = 1.0f / (float)(B_ * N_);

    float sum = 0.0f;
    for (int t = blockIdx.x * 256 + threadIdx.x; t < Q; t += RB * 256) {
        const int zb = t >> 13;              // t / N_
        const int qn = t & (N_ - 1);
        const float* p = part + ((size_t)zb * RCH) * N_ + qn;
        float m = p[0];
#pragma unroll
        for (int c = 1; c < RCH; ++c) m = fminf(m, p[(size_t)c * N_]);
        float d = sqrtf(m + EPS);
        sum += (zb < 4) ? d * w[(size_t)zb * N_ + qn] : d;
    }
    sum *= invBN;

    __shared__ float ss[256 / 64];
    int lane = threadIdx.x & 63;
    int wid  = threadIdx.x >> 6;
#pragma unroll
    for (int off = 32; off > 0; off >>= 1) sum += __shfl_down(sum, off);
    if (lane == 0) ss[wid] = sum;
    __syncthreads();
    if (threadIdx.x == 0) {
        float s = 0.0f;
#pragma unroll
        for (int i = 0; i < 256 / 64; ++i) s += ss[i];
        atomicAdd(out, s);
    }
}

extern "C" void kernel_launch(void* const* d_in, const int* in_sizes, int n_in,
                              void* d_out, int out_size, void* d_ws, size_t ws_size,
                              hipStream_t stream)
{
    const float* src = (const float*)d_in[0];   // (B, N, 3)
    const float* tgt = (const float*)d_in[1];   // (B, M, 3)
    const float* w   = (const float*)d_in[2];   // (B, N)
    float* out = (float*)d_out;

    float* part = (float*)d_ws;   // [2*B][RCH][N] = 2 MB, fully overwritten

    dim3 grid(N_ / QPB, RCH, 2 * B_);   // 32 x 8 x 8 = 2048 blocks
    nn_mfma_kernel<<<grid, TPB, 0, stream>>>(src, tgt, part, out);

    reduce_kernel<<<RB, 256, 0, stream>>>(part, w, out);
}